// Round 4
// baseline (43073.648 us; speedup 1.0000x reference)
//
#include <hip/hip_runtime.h>
#include <hip/hip_cooperative_groups.h>
#include <math.h>

namespace cg = cooperative_groups;

#define NCH   128          // chains = 2*B (0..63 = generated, 64..127 = true)
#define SLEN  256
#define HDIM  1024
#define N3    3072

typedef __attribute__((ext_vector_type(8))) __bf16 bf16x8;
typedef __attribute__((ext_vector_type(4))) __bf16 bf16x4;
typedef __attribute__((ext_vector_type(4))) float  f32x4;

__device__ __forceinline__ f32x4 mfma_bf16(bf16x8 a, bf16x8 b, f32x4 c) {
  return __builtin_amdgcn_mfma_f32_16x16x32_bf16(a, b, c, 0, 0, 0);
}

// ---------------------------------------------------------------------------
__global__ void split_w(const float* __restrict__ src, __bf16* __restrict__ dh,
                        __bf16* __restrict__ dl, int n)
{
  int i = blockIdx.x * blockDim.x + threadIdx.x;
  if (i < n) {
    float x = src[i];
    __bf16 h = (__bf16)x;
    float r = x - (float)h;
    dh[i] = h;
    dl[i] = (__bf16)r;
  }
}

__global__ void zero_kernel(float* __restrict__ p, int n)
{
  int i = blockIdx.x * blockDim.x + threadIdx.x;
  if (i < n) p[i] = 0.f;
}

// ---------------------------------------------------------------------------
// xproj_mfma: out[r, n] = x_row(r) @ W[n, :] + bias[n], split-bf16 3-pass MFMA.
// (unchanged from R3 — verified correct)
// ---------------------------------------------------------------------------
__global__ __launch_bounds__(256) void xproj_mfma(
    const float* __restrict__ A0, const float* __restrict__ A1,
    int chainsA0, int strideChain, int t0, int K, int lTc,
    const __bf16* __restrict__ Wh, const __bf16* __restrict__ Wl,
    const float* __restrict__ bias, float* __restrict__ out)
{
  __shared__ __bf16 Ah[4][128][8];
  __shared__ __bf16 Al[4][128][8];
  const int tid  = threadIdx.x;
  const int n0   = blockIdx.x * 64;
  const int row0 = blockIdx.y * 128;
  const int lane = tid & 63;
  const int wv   = tid >> 6;
  const int q    = lane >> 4;
  const int c15  = lane & 15;
  const int m_off = wv * 32;
  const int sr  = tid >> 1;
  const int sq0 = (tid & 1) * 2;
  const int sk  = (tid & 1) * 16;
  const int r     = row0 + sr;
  const int chain = r >> lTc;
  const int dt    = r & ((1 << lTc) - 1);
  const float* aptr = (chain < chainsA0)
      ? (A0 + ((size_t)chain * strideChain + t0 + dt) * K)
      : (A1 + ((size_t)(chain - chainsA0) * strideChain + t0 + dt) * K);

  f32x4 acc[2][4];
#pragma unroll
  for (int i = 0; i < 2; ++i)
#pragma unroll
    for (int j = 0; j < 4; ++j) acc[i][j] = (f32x4){0.f, 0.f, 0.f, 0.f};

  for (int k0 = 0; k0 < K; k0 += 32) {
    float f[16];
    *(float4*)(f + 0)  = *(const float4*)(aptr + k0 + sk + 0);
    *(float4*)(f + 4)  = *(const float4*)(aptr + k0 + sk + 4);
    *(float4*)(f + 8)  = *(const float4*)(aptr + k0 + sk + 8);
    *(float4*)(f + 12) = *(const float4*)(aptr + k0 + sk + 12);
    bf16x8 hv0, hv1, lv0, lv1;
#pragma unroll
    for (int e = 0; e < 8; ++e) {
      __bf16 h0 = (__bf16)f[e];
      hv0[e] = h0;  lv0[e] = (__bf16)(f[e] - (float)h0);
      __bf16 h1 = (__bf16)f[8 + e];
      hv1[e] = h1;  lv1[e] = (__bf16)(f[8 + e] - (float)h1);
    }
    __syncthreads();
    *(bf16x8*)&Ah[sq0][sr][0]     = hv0;
    *(bf16x8*)&Ah[sq0 + 1][sr][0] = hv1;
    *(bf16x8*)&Al[sq0][sr][0]     = lv0;
    *(bf16x8*)&Al[sq0 + 1][sr][0] = lv1;
    __syncthreads();

    bf16x8 a_h[2], a_l[2];
#pragma unroll
    for (int i = 0; i < 2; ++i) {
      a_h[i] = *(const bf16x8*)&Ah[q][m_off + i * 16 + c15][0];
      a_l[i] = *(const bf16x8*)&Al[q][m_off + i * 16 + c15][0];
    }
#pragma unroll
    for (int j = 0; j < 4; ++j) {
      const size_t woff = (size_t)(n0 + j * 16 + c15) * K + k0 + q * 8;
      bf16x8 b_h = *(const bf16x8*)(Wh + woff);
      bf16x8 b_l = *(const bf16x8*)(Wl + woff);
#pragma unroll
      for (int i = 0; i < 2; ++i) {
        acc[i][j] = mfma_bf16(a_h[i], b_h, acc[i][j]);
        acc[i][j] = mfma_bf16(a_h[i], b_l, acc[i][j]);
        acc[i][j] = mfma_bf16(a_l[i], b_h, acc[i][j]);
      }
    }
  }

#pragma unroll
  for (int j = 0; j < 4; ++j) {
    const int col = n0 + j * 16 + c15;
    const float bcol = bias[col];
#pragma unroll
    for (int i = 0; i < 2; ++i) {
#pragma unroll
      for (int rr = 0; rr < 4; ++rr) {
        const int m = m_off + i * 16 + q * 4 + rr;
        out[(size_t)(row0 + m) * N3 + col] = acc[i][j][rr] + bcol;
      }
    }
  }
}

// ---------------------------------------------------------------------------
// ln_rows: in-place LayerNorm per gate over H for each row (unchanged).
// ---------------------------------------------------------------------------
__global__ __launch_bounds__(256) void ln_rows(float* __restrict__ a,
    const float* __restrict__ gw, const float* __restrict__ gb)
{
  const int row = blockIdx.x;
  const int tid = threadIdx.x;
  float* base = a + (size_t)row * N3;
  __shared__ float redS[4], redS2[4];
  __shared__ float s_mean, s_rstd;
  for (int g = 0; g < 3; ++g) {
    const int j = g * 1024 + tid * 4;
    float4 v = *(const float4*)(base + j);
    float s  = v.x + v.y + v.z + v.w;
    float s2 = v.x*v.x + v.y*v.y + v.z*v.z + v.w*v.w;
#pragma unroll
    for (int off = 32; off > 0; off >>= 1) {
      s  += __shfl_down(s, off);
      s2 += __shfl_down(s2, off);
    }
    if ((tid & 63) == 0) { redS[tid >> 6] = s; redS2[tid >> 6] = s2; }
    __syncthreads();
    if (tid == 0) {
      float S  = redS[0] + redS[1] + redS[2] + redS[3];
      float S2 = redS2[0] + redS2[1] + redS2[2] + redS2[3];
      float mean = S * (1.f / 1024.f);
      float var  = S2 * (1.f / 1024.f) - mean * mean;
      s_mean = mean;
      s_rstd = rsqrtf(var + 1e-5f);
    }
    __syncthreads();
    float mean = s_mean, rstd = s_rstd;
    float4 gwv = *(const float4*)(gw + j);
    float4 gbv = *(const float4*)(gb + j);
    float4 o;
    o.x = (v.x - mean) * rstd * gwv.x + gbv.x;
    o.y = (v.y - mean) * rstd * gwv.y + gbv.y;
    o.z = (v.z - mean) * rstd * gwv.z + gbv.z;
    o.w = (v.w - mean) * rstd * gwv.w + gbv.w;
    *(float4*)(base + j) = o;
    __syncthreads();
  }
}

// ---------------------------------------------------------------------------
// emit_stats: butterfly-reduce (sum, sumsq) over the 16 c15 lanes, then one
// atomicAdd per (chain, gate, stat) from the c15==0 lanes.
// ---------------------------------------------------------------------------
__device__ __forceinline__ void emit_stats(f32x4 s, f32x4 s2, float* sbase,
    int gate, int chbase)
{
#pragma unroll
  for (int m = 1; m < 16; m <<= 1) {
#pragma unroll
    for (int rr = 0; rr < 4; ++rr) {
      s[rr]  += __shfl_xor(s[rr], m);
      s2[rr] += __shfl_xor(s2[rr], m);
    }
  }
  if ((threadIdx.x & 15) == 0) {
#pragma unroll
    for (int rr = 0; rr < 4; ++rr) {
      const int ch = chbase + rr;
      atomicAdd(sbase + (ch * 3 + gate) * 2 + 0, s[rr]);
      atomicAdd(sbase + (ch * 3 + gate) * 2 + 1, s2[rr]);
    }
  }
}

// ---------------------------------------------------------------------------
// recur_coop: the whole recurrence for one layer chunk in ONE cooperative
// kernel. Grid 128 blocks x 256 thr. Block (mt,ct): chains [mt*32,+32),
// cols [ct*32,+32) of each of the 3 gates. Per step:
//   A: split-bf16 MFMA h@Whh^T slice (frags from L2) + bias, LN-stat atomics
//   grid.sync()
//   B: normalize (stats from global), LDS exchange r/z/n, gate math,
//      write h (fp32 + hi/lo bf16) [+ h0seq for layer 0]
//   grid.sync()
// blockIdx = mt*32 + ct so each XCD sees ~4 distinct col-slices of Whh
// (~1.5 MB) -> L2-resident weights.
// ---------------------------------------------------------------------------
__global__ __launch_bounds__(256) void recur_coop(
    const __bf16* __restrict__ Wh, const __bf16* __restrict__ Wl,
    const float* __restrict__ bhh,
    const float* __restrict__ ghw, const float* __restrict__ ghb,
    const float* __restrict__ pi,
    float* __restrict__ h_cur, __bf16* __restrict__ Hh, __bf16* __restrict__ Hl,
    float* __restrict__ h0seq, float* __restrict__ stats, int Tc)
{
  cg::grid_group grid = cg::this_grid();
  const int tid  = threadIdx.x;
  const int bid  = blockIdx.x;       // 0..127
  const int ct   = bid & 31;
  const int mt   = bid >> 5;
  const int m0   = mt * 32;
  const int j0   = ct * 32;
  const int lane = tid & 63;
  const int wv   = tid >> 6;
  const int q    = lane >> 4;
  const int c15  = lane & 15;
  const int mi   = wv & 1;           // m-16-group within the 32-chain tile
  const int ng   = wv >> 1;          // n-tile group: 0 -> nt{0,1,2}, 1 -> nt{3,4,5}

  __shared__ float ph_lds[3][32][33];

  // zero the per-step stats buffer (whole launch), then sync
  const int statsN = Tc * NCH * 3 * 2;
  for (int i = bid * 256 + tid; i < statsN; i += gridDim.x * 256) stats[i] = 0.f;
  grid.sync();

  const size_t arow = (size_t)(m0 + mi * 16 + c15) * HDIM;
  int ncol[3]; size_t brow[3]; int half[3]; int gate_[3];
#pragma unroll
  for (int t = 0; t < 3; ++t) {
    const int nt = 3 * ng + t;
    gate_[t] = nt >> 1;
    half[t]  = nt & 1;
    ncol[t]  = gate_[t] * 1024 + j0 + half[t] * 16 + c15;
    brow[t]  = (size_t)ncol[t] * HDIM;
  }
  const int chbase = m0 + mi * 16 + q * 4;   // global chain of acc row rr=0
  const int chl0   = mi * 16 + q * 4;        // local chain within tile

  for (int dt = 0; dt < Tc; ++dt) {
    // ---- phase A: GEMM slice ----
    f32x4 acc[3];
#pragma unroll
    for (int t = 0; t < 3; ++t) acc[t] = (f32x4){0.f, 0.f, 0.f, 0.f};

    for (int k0 = 0; k0 < HDIM; k0 += 32) {
      const int k = k0 + q * 8;
      bf16x8 a_h = *(const bf16x8*)(Hh + arow + k);
      bf16x8 a_l = *(const bf16x8*)(Hl + arow + k);
#pragma unroll
      for (int t = 0; t < 3; ++t) {
        bf16x8 b_h = *(const bf16x8*)(Wh + brow[t] + k);
        bf16x8 b_l = *(const bf16x8*)(Wl + brow[t] + k);
        acc[t] = mfma_bf16(a_h, b_h, acc[t]);
        acc[t] = mfma_bf16(a_h, b_l, acc[t]);
        acc[t] = mfma_bf16(a_l, b_h, acc[t]);
      }
    }
#pragma unroll
    for (int t = 0; t < 3; ++t) {
      const float bb = bhh[ncol[t]];
#pragma unroll
      for (int rr = 0; rr < 4; ++rr) acc[t][rr] += bb;
    }

    // ---- LN stats (atomic partials) ----
    float* sbase = stats + (size_t)dt * NCH * 3 * 2;
    if (ng == 0) {
      f32x4 s01 = acc[0] + acc[1];
      f32x4 q01 = acc[0] * acc[0] + acc[1] * acc[1];
      emit_stats(s01, q01, sbase, 0, chbase);
      emit_stats(acc[2], acc[2] * acc[2], sbase, 1, chbase);
    } else {
      emit_stats(acc[0], acc[0] * acc[0], sbase, 1, chbase);
      f32x4 s12 = acc[1] + acc[2];
      f32x4 q12 = acc[1] * acc[1] + acc[2] * acc[2];
      emit_stats(s12, q12, sbase, 2, chbase);
    }
    grid.sync();

    // ---- phase B: normalize + exchange + gate math ----
#pragma unroll
    for (int t = 0; t < 3; ++t) {
      const int g = gate_[t];
      const float gm = ghw[ncol[t]];
      const float gb = ghb[ncol[t]];
#pragma unroll
      for (int rr = 0; rr < 4; ++rr) {
        const int ch = chbase + rr;
        const float S  = sbase[(ch * 3 + g) * 2 + 0];
        const float S2 = sbase[(ch * 3 + g) * 2 + 1];
        const float mean = S * (1.f / 1024.f);
        const float var  = S2 * (1.f / 1024.f) - mean * mean;
        const float rstd = rsqrtf(var + 1e-5f);
        ph_lds[g][chl0 + rr][half[t] * 16 + c15] =
            (acc[t][rr] - mean) * rstd * gm + gb;
      }
    }
    __syncthreads();

#pragma unroll
    for (int p = 0; p < 4; ++p) {
      const int flat = p * 256 + tid;
      const int chl  = flat >> 5;
      const int col  = flat & 31;
      const int ch   = m0 + chl;
      const int hcol = j0 + col;
      const float rv = ph_lds[0][chl][col];
      const float zv = ph_lds[1][chl][col];
      const float nv = ph_lds[2][chl][col];
      const float* pirow = pi + ((size_t)ch * Tc + dt) * N3 + hcol;
      const float pr = pirow[0];
      const float pz = pirow[1024];
      const float pn = pirow[2048];
      const float hp = h_cur[(size_t)ch * HDIM + hcol];
      const float r  = 1.f / (1.f + expf(-(pr + rv)));
      const float z  = 1.f / (1.f + expf(-(pz + zv)));
      const float nn = tanhf(pn + r * nv);
      const float hn = (1.f - z) * nn + z * hp;
      h_cur[(size_t)ch * HDIM + hcol] = hn;
      const __bf16 hb = (__bf16)hn;
      Hh[(size_t)ch * HDIM + hcol] = hb;
      Hl[(size_t)ch * HDIM + hcol] = (__bf16)(hn - (float)hb);
      if (h0seq)
        h0seq[((size_t)ch * Tc + dt) * HDIM + hcol] = hn;
    }
    grid.sync();
  }
}

// ---------------------------------------------------------------------------
__global__ __launch_bounds__(256) void label_kernel(const float* __restrict__ h,
    const float* __restrict__ Wout, const float* __restrict__ bout,
    float* __restrict__ labels)
{
  const int c = blockIdx.x;
  const int tid = threadIdx.x;
  __shared__ float red[4];
  float4 hv = *(const float4*)(h + (size_t)c * HDIM + tid * 4);
  float4 wv = *(const float4*)(Wout + tid * 4);
  float s = hv.x * wv.x + hv.y * wv.y + hv.z * wv.z + hv.w * wv.w;
#pragma unroll
  for (int off = 32; off > 0; off >>= 1) s += __shfl_down(s, off);
  if ((tid & 63) == 0) red[tid >> 6] = s;
  __syncthreads();
  if (tid == 0) labels[c] = red[0] + red[1] + red[2] + red[3] + bout[0];
}

__global__ void loss_kernel(const float* __restrict__ labels, float* __restrict__ out)
{
  const int tid = threadIdx.x;    // 128 threads
  __shared__ float rg[2], rt[2];
  float v = labels[tid];
  float g = (tid < 64) ? v : 0.f;
  float t = (tid >= 64) ? v : 0.f;
#pragma unroll
  for (int off = 32; off > 0; off >>= 1) {
    g += __shfl_down(g, off);
    t += __shfl_down(t, off);
  }
  if ((tid & 63) == 0) { rg[tid >> 6] = g; rt[tid >> 6] = t; }
  __syncthreads();
  if (tid == 0) {
    float gm = (rg[0] + rg[1]) * (1.f / 64.f);
    float tm = (rt[0] + rt[1]) * (1.f / 64.f);
    out[0] = -tm + gm;
    out[1] = -gm;
  }
}

// ---------------------------------------------------------------------------
extern "C" void kernel_launch(void* const* d_in, const int* in_sizes, int n_in,
                              void* d_out, int out_size, void* d_ws, size_t ws_size,
                              hipStream_t stream)
{
  const float* gen  = (const float*)d_in[0];
  const float* tru  = (const float*)d_in[1];
  const float* Wih0 = (const float*)d_in[2];
  const float* Whh0 = (const float*)d_in[3];
  const float* bih0 = (const float*)d_in[4];
  const float* bhh0 = (const float*)d_in[5];
  const float* gig0 = (const float*)d_in[6];
  const float* gib0 = (const float*)d_in[7];
  const float* ghg0 = (const float*)d_in[8];
  const float* ghb0 = (const float*)d_in[9];
  const float* Wih1 = (const float*)d_in[10];
  const float* Whh1 = (const float*)d_in[11];
  const float* bih1 = (const float*)d_in[12];
  const float* bhh1 = (const float*)d_in[13];
  const float* gig1 = (const float*)d_in[14];
  const float* gib1 = (const float*)d_in[15];
  const float* ghg1 = (const float*)d_in[16];
  const float* ghb1 = (const float*)d_in[17];
  const float* Wout = (const float*)d_in[18];
  const float* bout = (const float*)d_in[19];
  float* out = (float*)d_out;

  // ---- bf16 hi/lo region ----
  __bf16* bp = (__bf16*)d_ws;
  __bf16* Whh0h = bp;                 bp += (size_t)N3 * HDIM;
  __bf16* Whh0l = bp;                 bp += (size_t)N3 * HDIM;
  __bf16* Whh1h = bp;                 bp += (size_t)N3 * HDIM;
  __bf16* Whh1l = bp;                 bp += (size_t)N3 * HDIM;
  __bf16* Wih1h = bp;                 bp += (size_t)N3 * HDIM;
  __bf16* Wih1l = bp;                 bp += (size_t)N3 * HDIM;
  __bf16* Wih0h = bp;                 bp += (size_t)N3 * 512;
  __bf16* Wih0l = bp;                 bp += (size_t)N3 * 512;
  __bf16* hbf   = bp;                 bp += (size_t)4 * NCH * HDIM;
  const size_t bf16Bytes = (size_t)((char*)bp - (char*)d_ws);

  // ---- float region: pi_chunk | h0_chunk | h_cur0 | h_cur1 | labels | stats
  int Tc = 256;
  while (Tc > 1) {
    size_t needF = (size_t)NCH * Tc * (N3 + HDIM) + 2 * (size_t)NCH * HDIM
                 + 256 + (size_t)Tc * NCH * 3 * 2;
    if (bf16Bytes + needF * 4 <= ws_size) break;
    Tc >>= 1;
  }
  int lTc = 0;
  while ((1 << lTc) < Tc) ++lTc;

  float* fp       = (float*)((char*)d_ws + bf16Bytes);
  float* pi_chunk = fp;   fp += (size_t)NCH * Tc * N3;
  float* h0_chunk = fp;   fp += (size_t)NCH * Tc * HDIM;
  float* h_cur0   = fp;   fp += (size_t)NCH * HDIM;
  float* h_cur1   = fp;   fp += (size_t)NCH * HDIM;
  float* labels   = fp;   fp += 256;
  float* stats    = fp;   // Tc * 128 * 3 * 2

  __bf16* H0h = hbf;
  __bf16* H0l = hbf + (size_t)NCH * HDIM;
  __bf16* H1h = hbf + (size_t)2 * NCH * HDIM;
  __bf16* H1l = hbf + (size_t)3 * NCH * HDIM;

  // ---- weight split ----
  {
    const int nW = N3 * HDIM;
    split_w<<<(nW + 255) / 256, 256, 0, stream>>>(Whh0, Whh0h, Whh0l, nW);
    split_w<<<(nW + 255) / 256, 256, 0, stream>>>(Whh1, Whh1h, Whh1l, nW);
    split_w<<<(nW + 255) / 256, 256, 0, stream>>>(Wih1, Wih1h, Wih1l, nW);
    const int nW0 = N3 * 512;
    split_w<<<(nW0 + 255) / 256, 256, 0, stream>>>(Wih0, Wih0h, Wih0l, nW0);
  }
  zero_kernel<<<(2 * NCH * HDIM) / 256, 256, 0, stream>>>(h_cur0, 2 * NCH * HDIM);
  zero_kernel<<<(2 * NCH * HDIM) / 256, 256, 0, stream>>>((float*)hbf, 2 * NCH * HDIM);

  const int nChunks = SLEN / Tc;
  for (int cidx = 0; cidx < nChunks; ++cidx) {
    const int t0 = cidx * Tc;
    // ---- layer 0: xproj + LN ----
    xproj_mfma<<<dim3(48, Tc), 256, 0, stream>>>(
        gen, tru, 64, SLEN, t0, 512, lTc, Wih0h, Wih0l, bih0, pi_chunk);
    ln_rows<<<NCH * Tc, 256, 0, stream>>>(pi_chunk, gig0, gib0);
    // ---- layer 0 recurrence (one cooperative kernel) ----
    {
      const __bf16* a0 = Whh0h; const __bf16* a1 = Whh0l;
      const float* a2 = bhh0; const float* a3 = ghg0; const float* a4 = ghb0;
      const float* a5 = pi_chunk; float* a6 = h_cur0;
      __bf16* a7 = H0h; __bf16* a8 = H0l; float* a9 = h0_chunk;
      float* a10 = stats; int a11 = Tc;
      void* args[] = {&a0,&a1,&a2,&a3,&a4,&a5,&a6,&a7,&a8,&a9,&a10,&a11};
      hipLaunchCooperativeKernel((void*)recur_coop, dim3(128), dim3(256),
                                 args, 0, stream);
    }
    // ---- layer 1: xproj + LN from h0_chunk ----
    xproj_mfma<<<dim3(48, Tc), 256, 0, stream>>>(
        h0_chunk, h0_chunk, NCH, Tc, 0, 1024, lTc, Wih1h, Wih1l, bih1, pi_chunk);
    ln_rows<<<NCH * Tc, 256, 0, stream>>>(pi_chunk, gig1, gib1);
    // ---- layer 1 recurrence ----
    {
      const __bf16* a0 = Whh1h; const __bf16* a1 = Whh1l;
      const float* a2 = bhh1; const float* a3 = ghg1; const float* a4 = ghb1;
      const float* a5 = pi_chunk; float* a6 = h_cur1;
      __bf16* a7 = H1h; __bf16* a8 = H1l; float* a9 = nullptr;
      float* a10 = stats; int a11 = Tc;
      void* args[] = {&a0,&a1,&a2,&a3,&a4,&a5,&a6,&a7,&a8,&a9,&a10,&a11};
      hipLaunchCooperativeKernel((void*)recur_coop, dim3(128), dim3(256),
                                 args, 0, stream);
    }
  }

  // ---- readout ----
  label_kernel<<<NCH, 256, 0, stream>>>(h_cur1, Wout, bout, labels);
  loss_kernel<<<1, 128, 0, stream>>>(labels, out);
}

// Round 5
// 12759.310 us; speedup vs baseline: 3.3759x; 3.3759x over previous
//
#include <hip/hip_runtime.h>
#include <math.h>

#define NCH   128          // chains = 2*B (0..63 = generated, 64..127 = true)
#define SLEN  256
#define HDIM  1024
#define N3    3072

typedef __attribute__((ext_vector_type(8))) __bf16 bf16x8;
typedef __attribute__((ext_vector_type(4))) float  f32x4;

__device__ __forceinline__ f32x4 mfma_bf16(bf16x8 a, bf16x8 b, f32x4 c) {
  return __builtin_amdgcn_mfma_f32_16x16x32_bf16(a, b, c, 0, 0, 0);
}

// ---- agent-scope (sc1 / IC-coherent) accessors: cross-XCD visibility without fences
__device__ __forceinline__ float ld_sc1_f32(const float* p) {
  return __hip_atomic_load(p, __ATOMIC_RELAXED, __HIP_MEMORY_SCOPE_AGENT);
}
__device__ __forceinline__ void st_sc1_f32(float* p, float v) {
  __hip_atomic_store(p, v, __ATOMIC_RELAXED, __HIP_MEMORY_SCOPE_AGENT);
}
__device__ __forceinline__ unsigned long long ld_sc1_u64(const unsigned long long* p) {
  return __hip_atomic_load(p, __ATOMIC_RELAXED, __HIP_MEMORY_SCOPE_AGENT);
}
__device__ __forceinline__ void st_sc1_u32(unsigned int* p, unsigned int v) {
  __hip_atomic_store(p, v, __ATOMIC_RELAXED, __HIP_MEMORY_SCOPE_AGENT);
}

// ---------------------------------------------------------------------------
__global__ void split_w(const float* __restrict__ src, __bf16* __restrict__ dh,
                        __bf16* __restrict__ dl, int n)
{
  int i = blockIdx.x * blockDim.x + threadIdx.x;
  if (i < n) {
    float x = src[i];
    __bf16 h = (__bf16)x;
    float r = x - (float)h;
    dh[i] = h;
    dl[i] = (__bf16)r;
  }
}

__global__ void zero_kernel(float* __restrict__ p, int n)
{
  int i = blockIdx.x * blockDim.x + threadIdx.x;
  if (i < n) p[i] = 0.f;
}

// ---------------------------------------------------------------------------
// xproj_mfma (unchanged from R3 — verified): out[r,n] = x_row(r)@W[n,:]+bias[n]
// ---------------------------------------------------------------------------
__global__ __launch_bounds__(256) void xproj_mfma(
    const float* __restrict__ A0, const float* __restrict__ A1,
    int chainsA0, int strideChain, int t0, int K, int lTc,
    const __bf16* __restrict__ Wh, const __bf16* __restrict__ Wl,
    const float* __restrict__ bias, float* __restrict__ out)
{
  __shared__ __bf16 Ah[4][128][8];
  __shared__ __bf16 Al[4][128][8];
  const int tid  = threadIdx.x;
  const int n0   = blockIdx.x * 64;
  const int row0 = blockIdx.y * 128;
  const int lane = tid & 63;
  const int wv   = tid >> 6;
  const int q    = lane >> 4;
  const int c15  = lane & 15;
  const int m_off = wv * 32;
  const int sr  = tid >> 1;
  const int sq0 = (tid & 1) * 2;
  const int sk  = (tid & 1) * 16;
  const int r     = row0 + sr;
  const int chain = r >> lTc;
  const int dt    = r & ((1 << lTc) - 1);
  const float* aptr = (chain < chainsA0)
      ? (A0 + ((size_t)chain * strideChain + t0 + dt) * K)
      : (A1 + ((size_t)(chain - chainsA0) * strideChain + t0 + dt) * K);

  f32x4 acc[2][4];
#pragma unroll
  for (int i = 0; i < 2; ++i)
#pragma unroll
    for (int j = 0; j < 4; ++j) acc[i][j] = (f32x4){0.f, 0.f, 0.f, 0.f};

  for (int k0 = 0; k0 < K; k0 += 32) {
    float f[16];
    *(float4*)(f + 0)  = *(const float4*)(aptr + k0 + sk + 0);
    *(float4*)(f + 4)  = *(const float4*)(aptr + k0 + sk + 4);
    *(float4*)(f + 8)  = *(const float4*)(aptr + k0 + sk + 8);
    *(float4*)(f + 12) = *(const float4*)(aptr + k0 + sk + 12);
    bf16x8 hv0, hv1, lv0, lv1;
#pragma unroll
    for (int e = 0; e < 8; ++e) {
      __bf16 h0 = (__bf16)f[e];
      hv0[e] = h0;  lv0[e] = (__bf16)(f[e] - (float)h0);
      __bf16 h1 = (__bf16)f[8 + e];
      hv1[e] = h1;  lv1[e] = (__bf16)(f[8 + e] - (float)h1);
    }
    __syncthreads();
    *(bf16x8*)&Ah[sq0][sr][0]     = hv0;
    *(bf16x8*)&Ah[sq0 + 1][sr][0] = hv1;
    *(bf16x8*)&Al[sq0][sr][0]     = lv0;
    *(bf16x8*)&Al[sq0 + 1][sr][0] = lv1;
    __syncthreads();

    bf16x8 a_h[2], a_l[2];
#pragma unroll
    for (int i = 0; i < 2; ++i) {
      a_h[i] = *(const bf16x8*)&Ah[q][m_off + i * 16 + c15][0];
      a_l[i] = *(const bf16x8*)&Al[q][m_off + i * 16 + c15][0];
    }
#pragma unroll
    for (int j = 0; j < 4; ++j) {
      const size_t woff = (size_t)(n0 + j * 16 + c15) * K + k0 + q * 8;
      bf16x8 b_h = *(const bf16x8*)(Wh + woff);
      bf16x8 b_l = *(const bf16x8*)(Wl + woff);
#pragma unroll
      for (int i = 0; i < 2; ++i) {
        acc[i][j] = mfma_bf16(a_h[i], b_h, acc[i][j]);
        acc[i][j] = mfma_bf16(a_h[i], b_l, acc[i][j]);
        acc[i][j] = mfma_bf16(a_l[i], b_h, acc[i][j]);
      }
    }
  }

#pragma unroll
  for (int j = 0; j < 4; ++j) {
    const int col = n0 + j * 16 + c15;
    const float bcol = bias[col];
#pragma unroll
    for (int i = 0; i < 2; ++i) {
#pragma unroll
      for (int rr = 0; rr < 4; ++rr) {
        const int m = m_off + i * 16 + q * 4 + rr;
        out[(size_t)(row0 + m) * N3 + col] = acc[i][j][rr] + bcol;
      }
    }
  }
}

// ---------------------------------------------------------------------------
// ln_rows (unchanged)
// ---------------------------------------------------------------------------
__global__ __launch_bounds__(256) void ln_rows(float* __restrict__ a,
    const float* __restrict__ gw, const float* __restrict__ gb)
{
  const int row = blockIdx.x;
  const int tid = threadIdx.x;
  float* base = a + (size_t)row * N3;
  __shared__ float redS[4], redS2[4];
  __shared__ float s_mean, s_rstd;
  for (int g = 0; g < 3; ++g) {
    const int j = g * 1024 + tid * 4;
    float4 v = *(const float4*)(base + j);
    float s  = v.x + v.y + v.z + v.w;
    float s2 = v.x*v.x + v.y*v.y + v.z*v.z + v.w*v.w;
#pragma unroll
    for (int off = 32; off > 0; off >>= 1) {
      s  += __shfl_down(s, off);
      s2 += __shfl_down(s2, off);
    }
    if ((tid & 63) == 0) { redS[tid >> 6] = s; redS2[tid >> 6] = s2; }
    __syncthreads();
    if (tid == 0) {
      float S  = redS[0] + redS[1] + redS[2] + redS[3];
      float S2 = redS2[0] + redS2[1] + redS2[2] + redS2[3];
      float mean = S * (1.f / 1024.f);
      float var  = S2 * (1.f / 1024.f) - mean * mean;
      s_mean = mean;
      s_rstd = rsqrtf(var + 1e-5f);
    }
    __syncthreads();
    float mean = s_mean, rstd = s_rstd;
    float4 gwv = *(const float4*)(gw + j);
    float4 gbv = *(const float4*)(gb + j);
    float4 o;
    o.x = (v.x - mean) * rstd * gwv.x + gbv.x;
    o.y = (v.y - mean) * rstd * gwv.y + gbv.y;
    o.z = (v.z - mean) * rstd * gwv.z + gbv.z;
    o.w = (v.w - mean) * rstd * gwv.w + gbv.w;
    *(float4*)(base + j) = o;
    __syncthreads();
  }
}

// ---------------------------------------------------------------------------
// recur_pers: persistent recurrence. 256 blocks x 512 thr (8 waves).
// Group gid = bid>>5 owns chains [gid*16,+16) — groups are fully independent
// (LN is per-chain), so barriers are GROUP-local (32 blocks) via IC counters.
// Block ct = bid&31 owns cols [ct*32,+32) of each gate. Waves split K (128 ea)
// and hold their weight hi/lo slice in 192 VGPRs for the whole launch.
// Cross-block data (packed h, LN partials) moves via sc1 (IC), so no fences.
// ---------------------------------------------------------------------------
__global__ __launch_bounds__(512, 2) void recur_pers(
    const __bf16* __restrict__ Wh, const __bf16* __restrict__ Wl,
    const float* __restrict__ bhh,
    const float* __restrict__ ghw, const float* __restrict__ ghb,
    const float* __restrict__ pi,
    unsigned int* __restrict__ Hpk,      // [NCH][HDIM] u32: lo16=hi-bf16, hi16=lo-bf16
    float* __restrict__ h_carry,         // [NCH][HDIM] fp32, chunk carry
    float* __restrict__ hseq,            // layer0: [ch][Tc][HDIM]; layer1: null
    float* __restrict__ stats_part,      // [8][32][96]
    int* __restrict__ bar,               // [(2*Tc)*8*16]
    int Tc, int firstChunk)
{
  const int tid  = threadIdx.x;
  const int bid  = blockIdx.x;
  const int gid  = bid >> 5;
  const int ct   = bid & 31;
  const int lane = tid & 63;
  const int w    = tid >> 6;        // wave 0..7 -> k-slice
  const int q    = lane >> 4;
  const int c15  = lane & 15;
  // phase-B mapping
  const int m    = tid & 15;        // chain within group
  const int col  = tid >> 4;        // 0..31 within col slice
  const int ch   = gid * 16 + m;
  const int Hcol = ct * 32 + col;

  __shared__ float red[8 * 6 * 16 * 20];   // [w][nt][n16][m(20 pad)]
  __shared__ float sred[8 * 16 * 6];       // [w][m][g*2+st]
  __shared__ float sstat[96];

  // ---- preload weight fragments into registers (hi/lo) ----
  bf16x8 bh[6][4], bl[6][4];
  const int kw = w * 128;
#pragma unroll
  for (int t = 0; t < 6; ++t) {
    const int gate = t >> 1, half = t & 1;
    const size_t nrow = (size_t)(gate * 1024 + ct * 32 + half * 16 + c15);
#pragma unroll
    for (int kc = 0; kc < 4; ++kc) {
      const size_t off = nrow * HDIM + kw + kc * 32 + q * 8;
      bh[t][kc] = *(const bf16x8*)(Wh + off);
      bl[t][kc] = *(const bf16x8*)(Wl + off);
    }
  }

  // per-thread constants (phase B)
  const float bias0 = bhh[Hcol], bias1 = bhh[1024 + Hcol], bias2 = bhh[2048 + Hcol];
  const float lw0 = ghw[Hcol], lw1 = ghw[1024 + Hcol], lw2 = ghw[2048 + Hcol];
  const float lb0 = ghb[Hcol], lb1 = ghb[1024 + Hcol], lb2 = ghb[2048 + Hcol];
  float hprev = firstChunk ? 0.f : h_carry[(size_t)ch * HDIM + Hcol];

  const size_t arowbase = (size_t)(gid * 16 + c15) * HDIM;
  float* my_part = stats_part + ((size_t)gid * 32 + ct) * 96;

  for (int dt = 0; dt < Tc; ++dt) {
    // prefetch pi for phase B
    const float* pirow = pi + ((size_t)ch * Tc + dt) * N3 + Hcol;
    const float pr = pirow[0], pz = pirow[1024], pn = pirow[2048];

    // ---- phase A: GEMM slice (k-split across waves) ----
    f32x4 acc[6];
#pragma unroll
    for (int t = 0; t < 6; ++t) acc[t] = (f32x4){0.f, 0.f, 0.f, 0.f};

    unsigned long long abuf[2][4];
#pragma unroll
    for (int j = 0; j < 4; ++j) {
      abuf[0][j] = ld_sc1_u64((const unsigned long long*)(Hpk + arowbase + kw + 0 * 32 + q * 8) + j);
      abuf[1][j] = ld_sc1_u64((const unsigned long long*)(Hpk + arowbase + kw + 1 * 32 + q * 8) + j);
    }
#pragma unroll
    for (int kc = 0; kc < 4; ++kc) {
      unsigned int u[8];
#pragma unroll
      for (int j = 0; j < 4; ++j) {
        u[2 * j]     = (unsigned int)(abuf[kc & 1][j]);
        u[2 * j + 1] = (unsigned int)(abuf[kc & 1][j] >> 32);
      }
      union { unsigned int d[4]; bf16x8 v; } uah, ual;
#pragma unroll
      for (int d = 0; d < 4; ++d) {
        uah.d[d] = __builtin_amdgcn_perm(u[2 * d + 1], u[2 * d], 0x05040100u);
        ual.d[d] = __builtin_amdgcn_perm(u[2 * d + 1], u[2 * d], 0x07060302u);
      }
      if (kc < 2) {
#pragma unroll
        for (int j = 0; j < 4; ++j)
          abuf[kc & 1][j] = ld_sc1_u64(
              (const unsigned long long*)(Hpk + arowbase + kw + (kc + 2) * 32 + q * 8) + j);
      }
      bf16x8 ah = uah.v, al = ual.v;
#pragma unroll
      for (int t = 0; t < 6; ++t) {
        acc[t] = mfma_bf16(ah, bh[t][kc], acc[t]);
        acc[t] = mfma_bf16(ah, bl[t][kc], acc[t]);
        acc[t] = mfma_bf16(al, bh[t][kc], acc[t]);
      }
    }

    // ---- k-reduce via LDS ----
#pragma unroll
    for (int t = 0; t < 6; ++t) {
      const int idx = ((w * 6 + t) * 16 + c15) * 20 + q * 4;
      *(f32x4*)&red[idx] = acc[t];
    }
    __syncthreads();

    float phv0 = 0.f, phv1 = 0.f, phv2 = 0.f;
    {
      const int cn = col & 15;
      const int hi = col >> 4;
#pragma unroll
      for (int w8 = 0; w8 < 8; ++w8) {
        phv0 += red[((w8 * 6 + 0 * 2 + hi) * 16 + cn) * 20 + m];
        phv1 += red[((w8 * 6 + 1 * 2 + hi) * 16 + cn) * 20 + m];
        phv2 += red[((w8 * 6 + 2 * 2 + hi) * 16 + cn) * 20 + m];
      }
    }
    phv0 += bias0; phv1 += bias1; phv2 += bias2;

    // ---- block-partial LN stats: butterfly over this wave's 4 cols ----
    {
      float s0 = phv0, s1 = phv1, s2 = phv2;
      float q0 = phv0 * phv0, q1 = phv1 * phv1, q2 = phv2 * phv2;
#pragma unroll
      for (int mm = 16; mm <= 32; mm <<= 1) {
        s0 += __shfl_xor(s0, mm); q0 += __shfl_xor(q0, mm);
        s1 += __shfl_xor(s1, mm); q1 += __shfl_xor(q1, mm);
        s2 += __shfl_xor(s2, mm); q2 += __shfl_xor(q2, mm);
      }
      if (lane < 16) {
        const int b = (w * 16 + lane) * 6;
        sred[b + 0] = s0; sred[b + 1] = q0;
        sred[b + 2] = s1; sred[b + 3] = q1;
        sred[b + 4] = s2; sred[b + 5] = q2;
      }
    }
    __syncthreads();
    if (tid < 96) {
      // tid = (g*16 + m)*2 + st
      const int gg = tid >> 5;
      const int mm = (tid >> 1) & 15;
      const int st = tid & 1;
      float v = 0.f;
#pragma unroll
      for (int w8 = 0; w8 < 8; ++w8) v += sred[(w8 * 16 + mm) * 6 + gg * 2 + st];
      st_sc1_f32(&my_part[tid], v);
    }

    // ---- barrier 1 (group) ----
    {
      const int slot = ((dt * 2 + 0) * 8 + gid) * 16;
      __syncthreads();
      if (tid == 0) {
        __hip_atomic_fetch_add(&bar[slot], 1, __ATOMIC_RELAXED, __HIP_MEMORY_SCOPE_AGENT);
        while (__hip_atomic_load(&bar[slot], __ATOMIC_RELAXED, __HIP_MEMORY_SCOPE_AGENT) < 32)
          __builtin_amdgcn_s_sleep(2);
      }
      __syncthreads();
    }

    // ---- phase B: gather stats, normalize, gate math ----
    if (tid < 96) {
      float v = 0.f;
      const float* sp = stats_part + (size_t)gid * 32 * 96 + tid;
#pragma unroll 8
      for (int c = 0; c < 32; ++c) v += ld_sc1_f32(sp + c * 96);
      sstat[tid] = v;
    }
    __syncthreads();

    {
      const int b0 = (0 * 16 + m) * 2, b1 = (1 * 16 + m) * 2, b2 = (2 * 16 + m) * 2;
      const float mean0 = sstat[b0] * (1.f / 1024.f);
      const float var0  = sstat[b0 + 1] * (1.f / 1024.f) - mean0 * mean0;
      const float mean1 = sstat[b1] * (1.f / 1024.f);
      const float var1  = sstat[b1 + 1] * (1.f / 1024.f) - mean1 * mean1;
      const float mean2 = sstat[b2] * (1.f / 1024.f);
      const float var2  = sstat[b2 + 1] * (1.f / 1024.f) - mean2 * mean2;
      const float nh0 = (phv0 - mean0) * rsqrtf(var0 + 1e-5f) * lw0 + lb0;
      const float nh1 = (phv1 - mean1) * rsqrtf(var1 + 1e-5f) * lw1 + lb1;
      const float nh2 = (phv2 - mean2) * rsqrtf(var2 + 1e-5f) * lw2 + lb2;
      const float r  = 1.f / (1.f + expf(-(pr + nh0)));
      const float z  = 1.f / (1.f + expf(-(pz + nh1)));
      const float nn = tanhf(pn + r * nh2);
      const float hn = (1.f - z) * nn + z * hprev;
      hprev = hn;
      const __bf16 hb = (__bf16)hn;
      const __bf16 lo = (__bf16)(hn - (float)hb);
      unsigned short hs, ls;
      __builtin_memcpy(&hs, &hb, 2);
      __builtin_memcpy(&ls, &lo, 2);
      st_sc1_u32(Hpk + (size_t)ch * HDIM + Hcol,
                 (unsigned int)hs | ((unsigned int)ls << 16));
      if (hseq) hseq[((size_t)ch * Tc + dt) * HDIM + Hcol] = hn;
      if (dt == Tc - 1) h_carry[(size_t)ch * HDIM + Hcol] = hn;
    }

    // ---- barrier 2 (group) ----
    {
      const int slot = ((dt * 2 + 1) * 8 + gid) * 16;
      __syncthreads();
      if (tid == 0) {
        __hip_atomic_fetch_add(&bar[slot], 1, __ATOMIC_RELAXED, __HIP_MEMORY_SCOPE_AGENT);
        while (__hip_atomic_load(&bar[slot], __ATOMIC_RELAXED, __HIP_MEMORY_SCOPE_AGENT) < 32)
          __builtin_amdgcn_s_sleep(2);
      }
      __syncthreads();
    }
  }
}

// ---------------------------------------------------------------------------
__global__ __launch_bounds__(256) void label_kernel(const float* __restrict__ h,
    const float* __restrict__ Wout, const float* __restrict__ bout,
    float* __restrict__ labels)
{
  const int c = blockIdx.x;
  const int tid = threadIdx.x;
  __shared__ float red[4];
  float4 hv = *(const float4*)(h + (size_t)c * HDIM + tid * 4);
  float4 wv = *(const float4*)(Wout + tid * 4);
  float s = hv.x * wv.x + hv.y * wv.y + hv.z * wv.z + hv.w * wv.w;
#pragma unroll
  for (int off = 32; off > 0; off >>= 1) s += __shfl_down(s, off);
  if ((tid & 63) == 0) red[tid >> 6] = s;
  __syncthreads();
  if (tid == 0) labels[c] = red[0] + red[1] + red[2] + red[3] + bout[0];
}

__global__ void loss_kernel(const float* __restrict__ labels, float* __restrict__ out)
{
  const int tid = threadIdx.x;    // 128 threads
  __shared__ float rg[2], rt[2];
  float v = labels[tid];
  float g = (tid < 64) ? v : 0.f;
  float t = (tid >= 64) ? v : 0.f;
#pragma unroll
  for (int off = 32; off > 0; off >>= 1) {
    g += __shfl_down(g, off);
    t += __shfl_down(t, off);
  }
  if ((tid & 63) == 0) { rg[tid >> 6] = g; rt[tid >> 6] = t; }
  __syncthreads();
  if (tid == 0) {
    float gm = (rg[0] + rg[1]) * (1.f / 64.f);
    float tm = (rt[0] + rt[1]) * (1.f / 64.f);
    out[0] = -tm + gm;
    out[1] = -gm;
  }
}

// ---------------------------------------------------------------------------
extern "C" void kernel_launch(void* const* d_in, const int* in_sizes, int n_in,
                              void* d_out, int out_size, void* d_ws, size_t ws_size,
                              hipStream_t stream)
{
  const float* gen  = (const float*)d_in[0];
  const float* tru  = (const float*)d_in[1];
  const float* Wih0 = (const float*)d_in[2];
  const float* Whh0 = (const float*)d_in[3];
  const float* bih0 = (const float*)d_in[4];
  const float* bhh0 = (const float*)d_in[5];
  const float* gig0 = (const float*)d_in[6];
  const float* gib0 = (const float*)d_in[7];
  const float* ghg0 = (const float*)d_in[8];
  const float* ghb0 = (const float*)d_in[9];
  const float* Wih1 = (const float*)d_in[10];
  const float* Whh1 = (const float*)d_in[11];
  const float* bih1 = (const float*)d_in[12];
  const float* bhh1 = (const float*)d_in[13];
  const float* gig1 = (const float*)d_in[14];
  const float* gib1 = (const float*)d_in[15];
  const float* ghg1 = (const float*)d_in[16];
  const float* ghb1 = (const float*)d_in[17];
  const float* Wout = (const float*)d_in[18];
  const float* bout = (const float*)d_in[19];
  float* out = (float*)d_out;

  // ---- bf16 hi/lo weights ----
  __bf16* bp = (__bf16*)d_ws;
  __bf16* Whh0h = bp;  bp += (size_t)N3 * HDIM;
  __bf16* Whh0l = bp;  bp += (size_t)N3 * HDIM;
  __bf16* Whh1h = bp;  bp += (size_t)N3 * HDIM;
  __bf16* Whh1l = bp;  bp += (size_t)N3 * HDIM;
  __bf16* Wih1h = bp;  bp += (size_t)N3 * HDIM;
  __bf16* Wih1l = bp;  bp += (size_t)N3 * HDIM;
  __bf16* Wih0h = bp;  bp += (size_t)N3 * 512;
  __bf16* Wih0l = bp;  bp += (size_t)N3 * 512;
  // packed h (u32 per element) for both layers
  unsigned int* H0pk = (unsigned int*)bp;
  unsigned int* H1pk = H0pk + (size_t)NCH * HDIM;
  const size_t bf16Bytes = ((char*)(H1pk + (size_t)NCH * HDIM)) - (char*)d_ws;

  // ---- float region ----
  // pi_chunk NCH*Tc*N3 | h0_chunk NCH*Tc*HDIM | h_cur0/1 | labels | stats_part | bar
  const size_t fixedF = 2 * (size_t)NCH * HDIM + 256 + 8 * 32 * 96;
  int Tc = 256;
  while (Tc > 1) {
    size_t needF = (size_t)NCH * Tc * (N3 + HDIM) + fixedF + ((size_t)Tc * 256 + 256);
    if (bf16Bytes + needF * 4 <= ws_size) break;
    Tc >>= 1;
  }
  int lTc = 0;
  while ((1 << lTc) < Tc) ++lTc;

  float* fp       = (float*)((char*)d_ws + bf16Bytes);
  float* pi_chunk = fp;   fp += (size_t)NCH * Tc * N3;
  float* h0_chunk = fp;   fp += (size_t)NCH * Tc * HDIM;
  float* h_cur0   = fp;   fp += (size_t)NCH * HDIM;
  float* h_cur1   = fp;   fp += (size_t)NCH * HDIM;
  float* labels   = fp;   fp += 256;
  float* stats    = fp;   fp += 8 * 32 * 96;
  int*   bar      = (int*)fp;
  const int nbar  = Tc * 256 + 128;

  // ---- weight split (once per launch) ----
  {
    const int nW = N3 * HDIM;
    split_w<<<(nW + 255) / 256, 256, 0, stream>>>(Whh0, Whh0h, Whh0l, nW);
    split_w<<<(nW + 255) / 256, 256, 0, stream>>>(Whh1, Whh1h, Whh1l, nW);
    split_w<<<(nW + 255) / 256, 256, 0, stream>>>(Wih1, Wih1h, Wih1l, nW);
    const int nW0 = N3 * 512;
    split_w<<<(nW0 + 255) / 256, 256, 0, stream>>>(Wih0, Wih0h, Wih0l, nW0);
  }
  // zero packed h (both layers)
  zero_kernel<<<(2 * NCH * HDIM) / 256, 256, 0, stream>>>((float*)H0pk, 2 * NCH * HDIM);

  const int nChunks = SLEN / Tc;
  for (int cidx = 0; cidx < nChunks; ++cidx) {
    const int t0 = cidx * Tc;
    const int first = (cidx == 0) ? 1 : 0;
    // ---- layer 0: xproj + LN ----
    xproj_mfma<<<dim3(48, Tc), 256, 0, stream>>>(
        gen, tru, 64, SLEN, t0, 512, lTc, Wih0h, Wih0l, bih0, pi_chunk);
    ln_rows<<<NCH * Tc, 256, 0, stream>>>(pi_chunk, gig0, gib0);
    // ---- layer 0 recurrence ----
    zero_kernel<<<(nbar + 255) / 256, 256, 0, stream>>>((float*)bar, nbar);
    {
      const __bf16* a0 = Whh0h; const __bf16* a1 = Whh0l;
      const float* a2 = bhh0; const float* a3 = ghg0; const float* a4 = ghb0;
      const float* a5 = pi_chunk; unsigned int* a6 = H0pk; float* a7 = h_cur0;
      float* a8 = h0_chunk; float* a9 = stats; int* a10 = bar;
      int a11 = Tc; int a12 = first;
      void* args[] = {&a0,&a1,&a2,&a3,&a4,&a5,&a6,&a7,&a8,&a9,&a10,&a11,&a12};
      hipLaunchCooperativeKernel((void*)recur_pers, dim3(256), dim3(512),
                                 args, 0, stream);
    }
    // ---- layer 1: xproj + LN from h0_chunk ----
    xproj_mfma<<<dim3(48, Tc), 256, 0, stream>>>(
        h0_chunk, h0_chunk, NCH, Tc, 0, 1024, lTc, Wih1h, Wih1l, bih1, pi_chunk);
    ln_rows<<<NCH * Tc, 256, 0, stream>>>(pi_chunk, gig1, gib1);
    // ---- layer 1 recurrence ----
    zero_kernel<<<(nbar + 255) / 256, 256, 0, stream>>>((float*)bar, nbar);
    {
      const __bf16* a0 = Whh1h; const __bf16* a1 = Whh1l;
      const float* a2 = bhh1; const float* a3 = ghg1; const float* a4 = ghb1;
      const float* a5 = pi_chunk; unsigned int* a6 = H1pk; float* a7 = h_cur1;
      float* a8 = nullptr; float* a9 = stats; int* a10 = bar;
      int a11 = Tc; int a12 = first;
      void* args[] = {&a0,&a1,&a2,&a3,&a4,&a5,&a6,&a7,&a8,&a9,&a10,&a11,&a12};
      hipLaunchCooperativeKernel((void*)recur_pers, dim3(256), dim3(512),
                                 args, 0, stream);
    }
  }

  // ---- readout ----
  label_kernel<<<NCH, 256, 0, stream>>>(h_cur1, Wout, bout, labels);
  loss_kernel<<<1, 128, 0, stream>>>(labels, out);
}

// Round 6
// 9645.544 us; speedup vs baseline: 4.4657x; 1.3228x over previous
//
#include <hip/hip_runtime.h>
#include <math.h>

#define NCH   128          // chains = 2*B (0..63 = generated, 64..127 = true)
#define SLEN  256
#define HDIM  1024
#define N3    3072

typedef __attribute__((ext_vector_type(8))) __bf16 bf16x8;
typedef __attribute__((ext_vector_type(4))) float  f32x4;

__device__ __forceinline__ f32x4 mfma_bf16(bf16x8 a, bf16x8 b, f32x4 c) {
  return __builtin_amdgcn_mfma_f32_16x16x32_bf16(a, b, c, 0, 0, 0);
}

// ---- agent-scope (sc1 / IC-coherent) accessors
__device__ __forceinline__ float ld_sc1_f32(const float* p) {
  return __hip_atomic_load(p, __ATOMIC_RELAXED, __HIP_MEMORY_SCOPE_AGENT);
}
__device__ __forceinline__ void st_sc1_f32(float* p, float v) {
  __hip_atomic_store(p, v, __ATOMIC_RELAXED, __HIP_MEMORY_SCOPE_AGENT);
}
__device__ __forceinline__ unsigned long long ld_sc1_u64(const unsigned long long* p) {
  return __hip_atomic_load(p, __ATOMIC_RELAXED, __HIP_MEMORY_SCOPE_AGENT);
}
__device__ __forceinline__ void st_sc1_u32(unsigned int* p, unsigned int v) {
  __hip_atomic_store(p, v, __ATOMIC_RELAXED, __HIP_MEMORY_SCOPE_AGENT);
}
__device__ __forceinline__ int ld_sc1_i32(const int* p) {
  return __hip_atomic_load(p, __ATOMIC_RELAXED, __HIP_MEMORY_SCOPE_AGENT);
}
__device__ __forceinline__ void st_sc1_i32(int* p, int v) {
  __hip_atomic_store(p, v, __ATOMIC_RELAXED, __HIP_MEMORY_SCOPE_AGENT);
}

// ---------------------------------------------------------------------------
__global__ void split_w(const float* __restrict__ src, __bf16* __restrict__ dh,
                        __bf16* __restrict__ dl, int n)
{
  int i = blockIdx.x * blockDim.x + threadIdx.x;
  if (i < n) {
    float x = src[i];
    __bf16 h = (__bf16)x;
    float r = x - (float)h;
    dh[i] = h;
    dl[i] = (__bf16)r;
  }
}

__global__ void zero_kernel(float* __restrict__ p, int n)
{
  int i = blockIdx.x * blockDim.x + threadIdx.x;
  if (i < n) p[i] = 0.f;
}

// ---------------------------------------------------------------------------
// xproj_mfma (unchanged — verified): out[r,n] = x_row(r)@W[n,:]+bias[n]
// ---------------------------------------------------------------------------
__global__ __launch_bounds__(256) void xproj_mfma(
    const float* __restrict__ A0, const float* __restrict__ A1,
    int chainsA0, int strideChain, int t0, int K, int lTc,
    const __bf16* __restrict__ Wh, const __bf16* __restrict__ Wl,
    const float* __restrict__ bias, float* __restrict__ out)
{
  __shared__ __bf16 Ah[4][128][8];
  __shared__ __bf16 Al[4][128][8];
  const int tid  = threadIdx.x;
  const int n0   = blockIdx.x * 64;
  const int row0 = blockIdx.y * 128;
  const int lane = tid & 63;
  const int wv   = tid >> 6;
  const int q    = lane >> 4;
  const int c15  = lane & 15;
  const int m_off = wv * 32;
  const int sr  = tid >> 1;
  const int sq0 = (tid & 1) * 2;
  const int sk  = (tid & 1) * 16;
  const int r     = row0 + sr;
  const int chain = r >> lTc;
  const int dt    = r & ((1 << lTc) - 1);
  const float* aptr = (chain < chainsA0)
      ? (A0 + ((size_t)chain * strideChain + t0 + dt) * K)
      : (A1 + ((size_t)(chain - chainsA0) * strideChain + t0 + dt) * K);

  f32x4 acc[2][4];
#pragma unroll
  for (int i = 0; i < 2; ++i)
#pragma unroll
    for (int j = 0; j < 4; ++j) acc[i][j] = (f32x4){0.f, 0.f, 0.f, 0.f};

  for (int k0 = 0; k0 < K; k0 += 32) {
    float f[16];
    *(float4*)(f + 0)  = *(const float4*)(aptr + k0 + sk + 0);
    *(float4*)(f + 4)  = *(const float4*)(aptr + k0 + sk + 4);
    *(float4*)(f + 8)  = *(const float4*)(aptr + k0 + sk + 8);
    *(float4*)(f + 12) = *(const float4*)(aptr + k0 + sk + 12);
    bf16x8 hv0, hv1, lv0, lv1;
#pragma unroll
    for (int e = 0; e < 8; ++e) {
      __bf16 h0 = (__bf16)f[e];
      hv0[e] = h0;  lv0[e] = (__bf16)(f[e] - (float)h0);
      __bf16 h1 = (__bf16)f[8 + e];
      hv1[e] = h1;  lv1[e] = (__bf16)(f[8 + e] - (float)h1);
    }
    __syncthreads();
    *(bf16x8*)&Ah[sq0][sr][0]     = hv0;
    *(bf16x8*)&Ah[sq0 + 1][sr][0] = hv1;
    *(bf16x8*)&Al[sq0][sr][0]     = lv0;
    *(bf16x8*)&Al[sq0 + 1][sr][0] = lv1;
    __syncthreads();

    bf16x8 a_h[2], a_l[2];
#pragma unroll
    for (int i = 0; i < 2; ++i) {
      a_h[i] = *(const bf16x8*)&Ah[q][m_off + i * 16 + c15][0];
      a_l[i] = *(const bf16x8*)&Al[q][m_off + i * 16 + c15][0];
    }
#pragma unroll
    for (int j = 0; j < 4; ++j) {
      const size_t woff = (size_t)(n0 + j * 16 + c15) * K + k0 + q * 8;
      bf16x8 b_h = *(const bf16x8*)(Wh + woff);
      bf16x8 b_l = *(const bf16x8*)(Wl + woff);
#pragma unroll
      for (int i = 0; i < 2; ++i) {
        acc[i][j] = mfma_bf16(a_h[i], b_h, acc[i][j]);
        acc[i][j] = mfma_bf16(a_h[i], b_l, acc[i][j]);
        acc[i][j] = mfma_bf16(a_l[i], b_h, acc[i][j]);
      }
    }
  }

#pragma unroll
  for (int j = 0; j < 4; ++j) {
    const int col = n0 + j * 16 + c15;
    const float bcol = bias[col];
#pragma unroll
    for (int i = 0; i < 2; ++i) {
#pragma unroll
      for (int rr = 0; rr < 4; ++rr) {
        const int m = m_off + i * 16 + q * 4 + rr;
        out[(size_t)(row0 + m) * N3 + col] = acc[i][j][rr] + bcol;
      }
    }
  }
}

// ---------------------------------------------------------------------------
// ln_rows (unchanged)
// ---------------------------------------------------------------------------
__global__ __launch_bounds__(256) void ln_rows(float* __restrict__ a,
    const float* __restrict__ gw, const float* __restrict__ gb)
{
  const int row = blockIdx.x;
  const int tid = threadIdx.x;
  float* base = a + (size_t)row * N3;
  __shared__ float redS[4], redS2[4];
  __shared__ float s_mean, s_rstd;
  for (int g = 0; g < 3; ++g) {
    const int j = g * 1024 + tid * 4;
    float4 v = *(const float4*)(base + j);
    float s  = v.x + v.y + v.z + v.w;
    float s2 = v.x*v.x + v.y*v.y + v.z*v.z + v.w*v.w;
#pragma unroll
    for (int off = 32; off > 0; off >>= 1) {
      s  += __shfl_down(s, off);
      s2 += __shfl_down(s2, off);
    }
    if ((tid & 63) == 0) { redS[tid >> 6] = s; redS2[tid >> 6] = s2; }
    __syncthreads();
    if (tid == 0) {
      float S  = redS[0] + redS[1] + redS[2] + redS[3];
      float S2 = redS2[0] + redS2[1] + redS2[2] + redS2[3];
      float mean = S * (1.f / 1024.f);
      float var  = S2 * (1.f / 1024.f) - mean * mean;
      s_mean = mean;
      s_rstd = rsqrtf(var + 1e-5f);
    }
    __syncthreads();
    float mean = s_mean, rstd = s_rstd;
    float4 gwv = *(const float4*)(gw + j);
    float4 gbv = *(const float4*)(gb + j);
    float4 o;
    o.x = (v.x - mean) * rstd * gwv.x + gbv.x;
    o.y = (v.y - mean) * rstd * gwv.y + gbv.y;
    o.z = (v.z - mean) * rstd * gwv.z + gbv.z;
    o.w = (v.w - mean) * rstd * gwv.w + gbv.w;
    *(float4*)(base + j) = o;
    __syncthreads();
  }
}

// ---------------------------------------------------------------------------
// recur_pers: persistent recurrence, flag-based group sync (no atomic RMW).
// 256 blocks x 512 thr. Group gid = bid>>5 owns chains [gid*16,+16); block
// ct = bid&31 owns cols [ct*32,+32) of each gate; waves split K, weights in
// registers. Cross-block data via sc1 (IC). Per-block sequence flags:
//   flag_a[gid*32+ct] = dt+1  after LN-partials written (phase A done)
//   flag_b[gid*32+ct] = dt+1  after h(dt) written        (phase B done)
// __syncthreads() before each flag store drains vmcnt on all waves (ordering).
// ---------------------------------------------------------------------------
__global__ __launch_bounds__(512, 2) void recur_pers(
    const __bf16* __restrict__ Wh, const __bf16* __restrict__ Wl,
    const float* __restrict__ bhh,
    const float* __restrict__ ghw, const float* __restrict__ ghb,
    const float* __restrict__ pi,
    unsigned int* __restrict__ Hpk,      // [NCH][HDIM] u32: lo16=hi-bf16, hi16=lo-bf16
    float* __restrict__ h_carry,         // [NCH][HDIM] fp32, chunk carry
    float* __restrict__ hseq,            // layer0: [ch][Tc][HDIM]; layer1: null
    float* __restrict__ stats_part,      // [8][32][96]  j = m*6 + g*2 + {sum,sumsq}
    int* __restrict__ flag_a, int* __restrict__ flag_b,   // [8*32]
    int Tc, int firstChunk)
{
  const int tid  = threadIdx.x;
  const int bid  = blockIdx.x;
  const int gid  = bid >> 5;
  const int ct   = bid & 31;
  const int lane = tid & 63;
  const int w    = tid >> 6;        // wave 0..7 -> k-slice
  const int q    = lane >> 4;
  const int c15  = lane & 15;
  // phase-B mapping
  const int m    = tid & 15;        // chain within group
  const int col  = tid >> 4;        // 0..31 within col slice
  const int ch   = gid * 16 + m;
  const int Hcol = ct * 32 + col;

  __shared__ float red[8 * 6 * 16 * 20];   // phase A: [w][nt][n16][m(20 pad)]; reused in B
  __shared__ float sred[8 * 16 * 6];       // [w][m][g*2+st]
  __shared__ float sstat[96];

  // ---- preload weight fragments into registers (hi/lo) ----
  bf16x8 bh[6][4], bl[6][4];
  const int kw = w * 128;
#pragma unroll
  for (int t = 0; t < 6; ++t) {
    const int gate = t >> 1, half = t & 1;
    const size_t nrow = (size_t)(gate * 1024 + ct * 32 + half * 16 + c15);
#pragma unroll
    for (int kc = 0; kc < 4; ++kc) {
      const size_t off = nrow * HDIM + kw + kc * 32 + q * 8;
      bh[t][kc] = *(const bf16x8*)(Wh + off);
      bl[t][kc] = *(const bf16x8*)(Wl + off);
    }
  }

  // per-thread constants (phase B)
  const float bias0 = bhh[Hcol], bias1 = bhh[1024 + Hcol], bias2 = bhh[2048 + Hcol];
  const float lw0 = ghw[Hcol], lw1 = ghw[1024 + Hcol], lw2 = ghw[2048 + Hcol];
  const float lb0 = ghb[Hcol], lb1 = ghb[1024 + Hcol], lb2 = ghb[2048 + Hcol];
  float hprev = firstChunk ? 0.f : h_carry[(size_t)ch * HDIM + Hcol];

  const size_t arowbase = (size_t)(gid * 16 + c15) * HDIM;
  float* my_part = stats_part + ((size_t)gid * 32 + ct) * 96;
  const int* fA = flag_a + (gid << 5);
  const int* fB = flag_b + (gid << 5);
  const int pidx = lane & 31;

  for (int dt = 0; dt < Tc; ++dt) {
    // prefetch pi for phase B (overlaps the poll)
    const float* pirow = pi + ((size_t)ch * Tc + dt) * N3 + Hcol;
    const float pr = pirow[0], pz = pirow[1024], pn = pirow[2048];

    // ---- wait until h(dt-1) published by all 32 blocks of the group ----
    if (w == 0 && dt > 0) {
      while (true) {
        int v = ld_sc1_i32(fB + pidx);
        if (!__any(v < dt)) break;
        __builtin_amdgcn_s_sleep(1);
      }
    }
    __syncthreads();
    __asm__ __volatile__("" ::: "memory");

    // ---- phase A: GEMM slice (k-split across waves) ----
    f32x4 acc[6];
#pragma unroll
    for (int t = 0; t < 6; ++t) acc[t] = (f32x4){0.f, 0.f, 0.f, 0.f};

    unsigned long long abuf[2][4];
#pragma unroll
    for (int j = 0; j < 4; ++j) {
      abuf[0][j] = ld_sc1_u64((const unsigned long long*)(Hpk + arowbase + kw + 0 * 32 + q * 8) + j);
      abuf[1][j] = ld_sc1_u64((const unsigned long long*)(Hpk + arowbase + kw + 1 * 32 + q * 8) + j);
    }
#pragma unroll
    for (int kc = 0; kc < 4; ++kc) {
      unsigned int u[8];
#pragma unroll
      for (int j = 0; j < 4; ++j) {
        u[2 * j]     = (unsigned int)(abuf[kc & 1][j]);
        u[2 * j + 1] = (unsigned int)(abuf[kc & 1][j] >> 32);
      }
      union { unsigned int d[4]; bf16x8 v; } uah, ual;
#pragma unroll
      for (int d = 0; d < 4; ++d) {
        uah.d[d] = __builtin_amdgcn_perm(u[2 * d + 1], u[2 * d], 0x05040100u);
        ual.d[d] = __builtin_amdgcn_perm(u[2 * d + 1], u[2 * d], 0x07060302u);
      }
      if (kc < 2) {
#pragma unroll
        for (int j = 0; j < 4; ++j)
          abuf[kc & 1][j] = ld_sc1_u64(
              (const unsigned long long*)(Hpk + arowbase + kw + (kc + 2) * 32 + q * 8) + j);
      }
      bf16x8 ah = uah.v, al = ual.v;
#pragma unroll
      for (int t = 0; t < 6; ++t) {
        acc[t] = mfma_bf16(ah, bh[t][kc], acc[t]);
        acc[t] = mfma_bf16(ah, bl[t][kc], acc[t]);
        acc[t] = mfma_bf16(al, bh[t][kc], acc[t]);
      }
    }

    // ---- k-reduce via LDS ----
#pragma unroll
    for (int t = 0; t < 6; ++t) {
      const int idx = ((w * 6 + t) * 16 + c15) * 20 + q * 4;
      *(f32x4*)&red[idx] = acc[t];
    }
    __syncthreads();

    float phv0 = 0.f, phv1 = 0.f, phv2 = 0.f;
    {
      const int cn = col & 15;
      const int hi = col >> 4;
#pragma unroll
      for (int w8 = 0; w8 < 8; ++w8) {
        phv0 += red[((w8 * 6 + 0 * 2 + hi) * 16 + cn) * 20 + m];
        phv1 += red[((w8 * 6 + 1 * 2 + hi) * 16 + cn) * 20 + m];
        phv2 += red[((w8 * 6 + 2 * 2 + hi) * 16 + cn) * 20 + m];
      }
    }
    phv0 += bias0; phv1 += bias1; phv2 += bias2;

    // ---- per-wave LN partials -> sred ----
    {
      float s0 = phv0, s1 = phv1, s2 = phv2;
      float q0 = phv0 * phv0, q1 = phv1 * phv1, q2 = phv2 * phv2;
#pragma unroll
      for (int mm = 16; mm <= 32; mm <<= 1) {
        s0 += __shfl_xor(s0, mm); q0 += __shfl_xor(q0, mm);
        s1 += __shfl_xor(s1, mm); q1 += __shfl_xor(q1, mm);
        s2 += __shfl_xor(s2, mm); q2 += __shfl_xor(q2, mm);
      }
      if (lane < 16) {
        const int b = (w * 16 + lane) * 6;
        sred[b + 0] = s0; sred[b + 1] = q0;
        sred[b + 2] = s1; sred[b + 3] = q1;
        sred[b + 4] = s2; sred[b + 5] = q2;
      }
    }
    __syncthreads();

    // ---- block partials -> IC (j = m*6 + g*2 + st, contiguous per chain) ----
    if (tid < 96) {
      const int m6 = tid / 6;
      const int r6 = tid - m6 * 6;
      float v = 0.f;
#pragma unroll
      for (int w8 = 0; w8 < 8; ++w8) v += sred[(w8 * 16 + m6) * 6 + r6];
      st_sc1_f32(&my_part[tid], v);
    }
    __syncthreads();   // drains vmcnt on all waves -> partials visible at IC
    if (tid == 0) st_sc1_i32((int*)fA + ct, dt + 1);

    // ---- wait all blocks' partials ----
    if (w == 0) {
      while (true) {
        int v = ld_sc1_i32(fA + pidx);
        if (!__any(v < dt + 1)) break;
        __builtin_amdgcn_s_sleep(1);
      }
    }
    __syncthreads();
    __asm__ __volatile__("" ::: "memory");

    // ---- gather stats: all 512 threads, 6 loads each; 2-stage reduce ----
    {
      const int cidx = tid >> 4;   // source block 0..31
      const float* sp = stats_part + ((size_t)gid * 32 + cidx) * 96 + m * 6;
      float p0 = ld_sc1_f32(sp + 0), p1 = ld_sc1_f32(sp + 1), p2 = ld_sc1_f32(sp + 2);
      float p3 = ld_sc1_f32(sp + 3), p4 = ld_sc1_f32(sp + 4), p5 = ld_sc1_f32(sp + 5);
      p0 += __shfl_xor(p0, 16); p1 += __shfl_xor(p1, 16); p2 += __shfl_xor(p2, 16);
      p3 += __shfl_xor(p3, 16); p4 += __shfl_xor(p4, 16); p5 += __shfl_xor(p5, 16);
      p0 += __shfl_xor(p0, 32); p1 += __shfl_xor(p1, 32); p2 += __shfl_xor(p2, 32);
      p3 += __shfl_xor(p3, 32); p4 += __shfl_xor(p4, 32); p5 += __shfl_xor(p5, 32);
      if (lane < 16) {           // per-wave partial over its 4 source blocks
        const int b = w * 104 + lane * 6;    // reuse `red`, stride 104 (bank-safe)
        red[b + 0] = p0; red[b + 1] = p1; red[b + 2] = p2;
        red[b + 3] = p3; red[b + 4] = p4; red[b + 5] = p5;
      }
    }
    __syncthreads();
    if (tid < 96) {
      float v = 0.f;
#pragma unroll
      for (int w8 = 0; w8 < 8; ++w8) v += red[w8 * 104 + tid];
      sstat[tid] = v;
    }
    __syncthreads();

    // ---- phase B: normalize + gate math + publish h(dt) ----
    {
      const int b = m * 6;
      const float mean0 = sstat[b + 0] * (1.f / 1024.f);
      const float var0  = sstat[b + 1] * (1.f / 1024.f) - mean0 * mean0;
      const float mean1 = sstat[b + 2] * (1.f / 1024.f);
      const float var1  = sstat[b + 3] * (1.f / 1024.f) - mean1 * mean1;
      const float mean2 = sstat[b + 4] * (1.f / 1024.f);
      const float var2  = sstat[b + 5] * (1.f / 1024.f) - mean2 * mean2;
      const float nh0 = (phv0 - mean0) * rsqrtf(var0 + 1e-5f) * lw0 + lb0;
      const float nh1 = (phv1 - mean1) * rsqrtf(var1 + 1e-5f) * lw1 + lb1;
      const float nh2 = (phv2 - mean2) * rsqrtf(var2 + 1e-5f) * lw2 + lb2;
      const float r  = 1.f / (1.f + expf(-(pr + nh0)));
      const float z  = 1.f / (1.f + expf(-(pz + nh1)));
      const float nn = tanhf(pn + r * nh2);
      const float hn = (1.f - z) * nn + z * hprev;
      hprev = hn;
      const __bf16 hb = (__bf16)hn;
      const __bf16 lo = (__bf16)(hn - (float)hb);
      unsigned short hs, ls;
      __builtin_memcpy(&hs, &hb, 2);
      __builtin_memcpy(&ls, &lo, 2);
      st_sc1_u32(Hpk + (size_t)ch * HDIM + Hcol,
                 (unsigned int)hs | ((unsigned int)ls << 16));
      if (hseq) hseq[((size_t)ch * Tc + dt) * HDIM + Hcol] = hn;
      if (dt == Tc - 1) h_carry[(size_t)ch * HDIM + Hcol] = hn;
    }
    __syncthreads();   // drains vmcnt -> h visible at IC
    if (tid == 0) st_sc1_i32((int*)fB + ct, dt + 1);
  }
}

// ---------------------------------------------------------------------------
__global__ __launch_bounds__(256) void label_kernel(const float* __restrict__ h,
    const float* __restrict__ Wout, const float* __restrict__ bout,
    float* __restrict__ labels)
{
  const int c = blockIdx.x;
  const int tid = threadIdx.x;
  __shared__ float red[4];
  float4 hv = *(const float4*)(h + (size_t)c * HDIM + tid * 4);
  float4 wv = *(const float4*)(Wout + tid * 4);
  float s = hv.x * wv.x + hv.y * wv.y + hv.z * wv.z + hv.w * wv.w;
#pragma unroll
  for (int off = 32; off > 0; off >>= 1) s += __shfl_down(s, off);
  if ((tid & 63) == 0) red[tid >> 6] = s;
  __syncthreads();
  if (tid == 0) labels[c] = red[0] + red[1] + red[2] + red[3] + bout[0];
}

__global__ void loss_kernel(const float* __restrict__ labels, float* __restrict__ out)
{
  const int tid = threadIdx.x;    // 128 threads
  __shared__ float rg[2], rt[2];
  float v = labels[tid];
  float g = (tid < 64) ? v : 0.f;
  float t = (tid >= 64) ? v : 0.f;
#pragma unroll
  for (int off = 32; off > 0; off >>= 1) {
    g += __shfl_down(g, off);
    t += __shfl_down(t, off);
  }
  if ((tid & 63) == 0) { rg[tid >> 6] = g; rt[tid >> 6] = t; }
  __syncthreads();
  if (tid == 0) {
    float gm = (rg[0] + rg[1]) * (1.f / 64.f);
    float tm = (rt[0] + rt[1]) * (1.f / 64.f);
    out[0] = -tm + gm;
    out[1] = -gm;
  }
}

// ---------------------------------------------------------------------------
extern "C" void kernel_launch(void* const* d_in, const int* in_sizes, int n_in,
                              void* d_out, int out_size, void* d_ws, size_t ws_size,
                              hipStream_t stream)
{
  const float* gen  = (const float*)d_in[0];
  const float* tru  = (const float*)d_in[1];
  const float* Wih0 = (const float*)d_in[2];
  const float* Whh0 = (const float*)d_in[3];
  const float* bih0 = (const float*)d_in[4];
  const float* bhh0 = (const float*)d_in[5];
  const float* gig0 = (const float*)d_in[6];
  const float* gib0 = (const float*)d_in[7];
  const float* ghg0 = (const float*)d_in[8];
  const float* ghb0 = (const float*)d_in[9];
  const float* Wih1 = (const float*)d_in[10];
  const float* Whh1 = (const float*)d_in[11];
  const float* bih1 = (const float*)d_in[12];
  const float* bhh1 = (const float*)d_in[13];
  const float* gig1 = (const float*)d_in[14];
  const float* gib1 = (const float*)d_in[15];
  const float* ghg1 = (const float*)d_in[16];
  const float* ghb1 = (const float*)d_in[17];
  const float* Wout = (const float*)d_in[18];
  const float* bout = (const float*)d_in[19];
  float* out = (float*)d_out;

  // ---- bf16 hi/lo weights ----
  __bf16* bp = (__bf16*)d_ws;
  __bf16* Whh0h = bp;  bp += (size_t)N3 * HDIM;
  __bf16* Whh0l = bp;  bp += (size_t)N3 * HDIM;
  __bf16* Whh1h = bp;  bp += (size_t)N3 * HDIM;
  __bf16* Whh1l = bp;  bp += (size_t)N3 * HDIM;
  __bf16* Wih1h = bp;  bp += (size_t)N3 * HDIM;
  __bf16* Wih1l = bp;  bp += (size_t)N3 * HDIM;
  __bf16* Wih0h = bp;  bp += (size_t)N3 * 512;
  __bf16* Wih0l = bp;  bp += (size_t)N3 * 512;
  unsigned int* H0pk = (unsigned int*)bp;
  unsigned int* H1pk = H0pk + (size_t)NCH * HDIM;
  const size_t bf16Bytes = ((char*)(H1pk + (size_t)NCH * HDIM)) - (char*)d_ws;

  // ---- float region ----
  const size_t fixedF = 2 * (size_t)NCH * HDIM + 256 + 8 * 32 * 96 + 1024;
  int Tc = 256;
  while (Tc > 1) {
    size_t needF = (size_t)NCH * Tc * (N3 + HDIM) + fixedF;
    if (bf16Bytes + needF * 4 <= ws_size) break;
    Tc >>= 1;
  }
  int lTc = 0;
  while ((1 << lTc) < Tc) ++lTc;

  float* fp       = (float*)((char*)d_ws + bf16Bytes);
  float* pi_chunk = fp;   fp += (size_t)NCH * Tc * N3;
  float* h0_chunk = fp;   fp += (size_t)NCH * Tc * HDIM;
  float* h_cur0   = fp;   fp += (size_t)NCH * HDIM;
  float* h_cur1   = fp;   fp += (size_t)NCH * HDIM;
  float* labels   = fp;   fp += 256;
  float* stats    = fp;   fp += 8 * 32 * 96;
  int*   flag_a   = (int*)fp;          // 256 ints
  int*   flag_b   = flag_a + 256;      // 256 ints (+ pad within 1024 floats)

  // ---- weight split (once per launch) ----
  {
    const int nW = N3 * HDIM;
    split_w<<<(nW + 255) / 256, 256, 0, stream>>>(Whh0, Whh0h, Whh0l, nW);
    split_w<<<(nW + 255) / 256, 256, 0, stream>>>(Whh1, Whh1h, Whh1l, nW);
    split_w<<<(nW + 255) / 256, 256, 0, stream>>>(Wih1, Wih1h, Wih1l, nW);
    const int nW0 = N3 * 512;
    split_w<<<(nW0 + 255) / 256, 256, 0, stream>>>(Wih0, Wih0h, Wih0l, nW0);
  }
  zero_kernel<<<(2 * NCH * HDIM) / 256, 256, 0, stream>>>((float*)H0pk, 2 * NCH * HDIM);

  const int nChunks = SLEN / Tc;
  for (int cidx = 0; cidx < nChunks; ++cidx) {
    const int t0 = cidx * Tc;
    const int first = (cidx == 0) ? 1 : 0;
    // ---- layer 0: xproj + LN ----
    xproj_mfma<<<dim3(48, Tc), 256, 0, stream>>>(
        gen, tru, 64, SLEN, t0, 512, lTc, Wih0h, Wih0l, bih0, pi_chunk);
    ln_rows<<<NCH * Tc, 256, 0, stream>>>(pi_chunk, gig0, gib0);
    // ---- layer 0 recurrence ----
    zero_kernel<<<2, 256, 0, stream>>>((float*)flag_a, 512);
    {
      const __bf16* a0 = Whh0h; const __bf16* a1 = Whh0l;
      const float* a2 = bhh0; const float* a3 = ghg0; const float* a4 = ghb0;
      const float* a5 = pi_chunk; unsigned int* a6 = H0pk; float* a7 = h_cur0;
      float* a8 = h0_chunk; float* a9 = stats; int* a10 = flag_a; int* a11 = flag_b;
      int a12 = Tc; int a13 = first;
      void* args[] = {&a0,&a1,&a2,&a3,&a4,&a5,&a6,&a7,&a8,&a9,&a10,&a11,&a12,&a13};
      hipLaunchCooperativeKernel((void*)recur_pers, dim3(256), dim3(512),
                                 args, 0, stream);
    }
    // ---- layer 1: xproj + LN from h0_chunk ----
    xproj_mfma<<<dim3(48, Tc), 256, 0, stream>>>(
        h0_chunk, h0_chunk, NCH, Tc, 0, 1024, lTc, Wih1h, Wih1l, bih1, pi_chunk);
    ln_rows<<<NCH * Tc, 256, 0, stream>>>(pi_chunk, gig1, gib1);
    // ---- layer 1 recurrence ----
    zero_kernel<<<2, 256, 0, stream>>>((float*)flag_a, 512);
    {
      const __bf16* a0 = Whh1h; const __bf16* a1 = Whh1l;
      const float* a2 = bhh1; const float* a3 = ghg1; const float* a4 = ghb1;
      const float* a5 = pi_chunk; unsigned int* a6 = H1pk; float* a7 = h_cur1;
      float* a8 = nullptr; float* a9 = stats; int* a10 = flag_a; int* a11 = flag_b;
      int a12 = Tc; int a13 = first;
      void* args[] = {&a0,&a1,&a2,&a3,&a4,&a5,&a6,&a7,&a8,&a9,&a10,&a11,&a12,&a13};
      hipLaunchCooperativeKernel((void*)recur_pers, dim3(256), dim3(512),
                                 args, 0, stream);
    }
  }

  // ---- readout ----
  label_kernel<<<NCH, 256, 0, stream>>>(h_cur1, Wout, bout, labels);
  loss_kernel<<<1, 128, 0, stream>>>(labels, out);
}